// Round 3
// baseline (274.204 us; speedup 1.0000x reference)
//
#include <hip/hip_runtime.h>
#include <cstdint>
#include <cstddef>

typedef unsigned short u16;
typedef short bf16x8 __attribute__((ext_vector_type(8)));
typedef float floatx4 __attribute__((ext_vector_type(4)));

#define GLD16(gp, sp) __builtin_amdgcn_global_load_lds(                      \
    (const __attribute__((address_space(1))) void*)(gp),                     \
    (__attribute__((address_space(3))) void*)(sp), 16, 0, 0)

__device__ __forceinline__ u16 f2bf(float f) {
  unsigned u = __float_as_uint(f);
  u += 0x7fffu + ((u >> 16) & 1u);   // round-to-nearest-even
  return (u16)(u >> 16);
}

// ---------------- fused prep ----------------
// regions: [0,1024) cvt_x | [1024,9216) w1^T | [9216,13312) w2^T | [13312,13824) router
// transpose: 64r x 32c f32 tile -> bf16 out[c][r]; 128-B read and write segments.
__global__ __launch_bounds__(256) void prep_kernel(
    const float* __restrict__ x, const float* __restrict__ rw, const float* __restrict__ rbias,
    const float* __restrict__ w1, const float* __restrict__ w2,
    u16* __restrict__ xb, u16* __restrict__ w1t, u16* __restrict__ w2t,
    float* __restrict__ ew, int* __restrict__ eids, float* __restrict__ eprobs) {
  __shared__ float lds[64 * 33];
  const int b = blockIdx.x, tid = threadIdx.x;
  if (b < 1024) {                       // ---- x f32 -> bf16
    const float4* in4 = (const float4*)x;
    ushort4* out4 = (ushort4*)xb;
    int i = (b << 8) + tid;
#pragma unroll
    for (int rep = 0; rep < 2; ++rep, i += 262144) {
      float4 v = in4[i];
      ushort4 o;
      o.x = f2bf(v.x); o.y = f2bf(v.y); o.z = f2bf(v.z); o.w = f2bf(v.w);
      out4[i] = o;
    }
  } else if (b < 13312) {               // ---- weight transpose+cvt
    const float* in; u16* out; int C, r0, c0;
    if (b < 9216) {
      int b2 = b - 1024, e = b2 >> 10, rem = b2 & 1023;   // 16 r-tiles x 64 c-tiles
      C = 2048; r0 = (rem >> 6) << 6; c0 = (rem & 63) << 5;
      in = w1 + (size_t)e * 2097152; out = w1t + (size_t)e * 2097152;
    } else {
      int b2 = b - 9216, e = b2 >> 9, rem = b2 & 511;     // 16 r-tiles x 32 c-tiles
      C = 1024; r0 = (rem >> 5) << 6; c0 = (rem & 31) << 5;
      in = w2 + (size_t)e * 1048576; out = w2t + (size_t)e * 1048576;
    }
    const int tx = tid & 31, ty = tid >> 5;
#pragma unroll
    for (int k = 0; k < 8; ++k) {
      int row = k * 8 + ty;
      lds[row * 33 + tx] = in[(size_t)(r0 + row) * C + c0 + tx];
    }
    __syncthreads();
#pragma unroll
    for (int k = 0; k < 4; ++k) {
      int cc = k * 8 + ty;
      ushort2 v;
      v.x = f2bf(lds[(tx * 2) * 33 + cc]);
      v.y = f2bf(lds[(tx * 2 + 1) * 33 + cc]);
      *(ushort2*)(out + (size_t)(c0 + cc) * 1024 + r0 + tx * 2) = v;
    }
  } else {                              // ---- router (4 tokens/block, 1 wave each)
    const int wave = tid >> 6, lane = tid & 63;
    const int t = ((b - 13312) << 2) + wave;
    const float4* xv = (const float4*)(x + (size_t)t * 1024);
    float acc[8];
#pragma unroll
    for (int e = 0; e < 8; ++e) acc[e] = 0.f;
    for (int j = lane; j < 256; j += 64) {
      float4 xx = xv[j];
#pragma unroll
      for (int e = 0; e < 8; ++e) {
        float4 wv = ((const float4*)(rw + (size_t)e * 1024))[j];
        acc[e] += xx.x * wv.x + xx.y * wv.y + xx.z * wv.z + xx.w * wv.w;
      }
    }
#pragma unroll
    for (int e = 0; e < 8; ++e) {
      float v = acc[e];
#pragma unroll
      for (int off = 32; off > 0; off >>= 1) v += __shfl_down(v, off);
      acc[e] = v;
    }
    if (lane == 0) {
      float p[8];
      float mx = -1e30f;
#pragma unroll
      for (int e = 0; e < 8; ++e) { p[e] = acc[e] + rbias[e]; mx = fmaxf(mx, p[e]); }
      float sum = 0.f;
#pragma unroll
      for (int e = 0; e < 8; ++e) { p[e] = __expf(p[e] - mx); sum += p[e]; }
      float inv = 1.f / sum;
#pragma unroll
      for (int e = 0; e < 8; ++e) p[e] *= inv;
      int i0 = 0;
#pragma unroll
      for (int e = 1; e < 8; ++e) if (p[e] > p[i0]) i0 = e;
      int i1 = (i0 == 0) ? 1 : 0;
#pragma unroll
      for (int e = 0; e < 8; ++e) if (e != i0 && e != i1 && p[e] > p[i1]) i1 = e;
      ew[t * 2 + 0] = p[i0];
      ew[t * 2 + 1] = p[i1];
      eids[t * 2 + 0] = i0;
      eids[t * 2 + 1] = i1;
      eprobs[t * 2 + 0] = p[i0];
      eprobs[t * 2 + 1] = p[i1];
    }
  }
}

// ---------------- build per-expert token lists + work list (1 block) ----------------
// meta[0]=nWork, meta[1..39]=(e<<8)|rowBlock, meta[48+e]=slotBase[e]
__global__ void build_lists_kernel(const int* __restrict__ eids, const float* __restrict__ eprobs,
                                   int* __restrict__ row_token, float* __restrict__ row_scale,
                                   int* __restrict__ meta) {
  __shared__ int cnt[8], base[8], cur[8];
  const int tid = threadIdx.x;
  if (tid < 8) { cnt[tid] = 0; cur[tid] = 0; }
  __syncthreads();
  for (int t = tid; t < 2048; t += 256) {
    atomicAdd(&cnt[eids[t * 2 + 0]], 1);
    atomicAdd(&cnt[eids[t * 2 + 1]], 1);
  }
  __syncthreads();
  if (tid == 0) {
    int off = 0, w = 0;
    for (int e = 0; e < 8; ++e) {
      base[e] = off;
      meta[48 + e] = off;
      int nb = (cnt[e] + 127) >> 7;
      for (int rb = 0; rb < nb; ++rb) meta[1 + w++] = (e << 8) | rb;
      off += nb << 7;
    }
    meta[0] = w;  // <= 39
  }
  __syncthreads();
  for (int s = tid; s < 5120; s += 256) { row_token[s] = -1; row_scale[s] = 0.f; }
  __syncthreads();
  for (int t = tid; t < 2048; t += 256) {
#pragma unroll
    for (int k = 0; k < 2; ++k) {
      int e = eids[t * 2 + k];
      int s = base[e] + atomicAdd(&cur[e], 1);
      row_token[s] = t;
      row_scale[s] = eprobs[t * 2 + k];
    }
  }
}

// out[t,h] = p0*w2b[e0,h] + p1*w2b[e1,h]  (C-init for gemm2), float4
__global__ void bias_init_kernel(const int* __restrict__ eids, const float* __restrict__ eprobs,
                                 const float* __restrict__ w2b, float* __restrict__ out) {
  int idx = blockIdx.x * 256 + threadIdx.x;  // < 524288
  int t = idx >> 8, h4 = idx & 255;
  const float4* b4 = (const float4*)w2b;
  float4 v0 = b4[eids[2 * t] * 256 + h4];
  float4 v1 = b4[eids[2 * t + 1] * 256 + h4];
  float p0 = eprobs[2 * t], p1 = eprobs[2 * t + 1];
  float4 r;
  r.x = p0 * v0.x + p1 * v1.x;
  r.y = p0 * v0.y + p1 * v1.y;
  r.z = p0 * v0.z + p1 * v1.z;
  r.w = p0 * v0.w + p1 * v1.w;
  ((float4*)out)[idx] = r;
}

// ---------------- GEMM1: 128x64 tile, gathered rows, glu epilogue -> actS ----------------
// 1-D grid 1280: d -> xcd(d&7), colSel(0..3), work(0..39); colIdx = xcd+8*colSel
// chunk-major LDS groups (16 rows x 32k = 1 KiB): frag read = group*1024B + lane*16B, conflict-free
__global__ __launch_bounds__(256) void gemm1_act_kernel(
    const u16* __restrict__ xb, const u16* __restrict__ w1t,
    const float* __restrict__ w1b,
    const int* __restrict__ row_token, const float* __restrict__ row_scale,
    const int* __restrict__ meta, u16* __restrict__ actS) {
  const int d = blockIdx.x;
  const int xcd = d & 7, i = d >> 3;
  const int work = i >> 2;
  if (work >= meta[0]) return;
  const int colBase = (xcd + ((i & 3) << 3)) << 6;   // 0..31 * 64
  const int wk = meta[1 + work];
  const int e = wk >> 8, rb = wk & 255;
  const int slotB = meta[48 + e] + (rb << 7);
  __shared__ __align__(16) u16 As[4096];  // 128 rows x 32 k
  __shared__ __align__(16) u16 Bs[2048];  //  64 rows x 32 k
  const int tid = threadIdx.x, lane = tid & 63, wave = tid >> 6;
  const int row16 = lane & 15, chunk = lane >> 4;
  const u16* Bt = w1t + (size_t)e * 2097152;
  int tk0 = row_token[slotB + wave * 16 + row16];       if (tk0 < 0) tk0 = 0;
  int tk1 = row_token[slotB + (wave + 4) * 16 + row16]; if (tk1 < 0) tk1 = 0;
  const u16* aP0 = xb + (size_t)tk0 * 1024 + chunk * 8;
  const u16* aP1 = xb + (size_t)tk1 * 1024 + chunk * 8;
  const u16* bP  = Bt + (size_t)(colBase + wave * 16 + row16) * 1024 + chunk * 8;
  const int wr = wave >> 1, wc = wave & 1;
  floatx4 acc[4][2];
#pragma unroll
  for (int mi = 0; mi < 4; ++mi)
#pragma unroll
    for (int ni = 0; ni < 2; ++ni) acc[mi][ni] = floatx4{0.f, 0.f, 0.f, 0.f};

  for (int kt = 0; kt < 32; ++kt) {
    const int k = kt * 32;
    GLD16(aP0 + k, As + wave * 512);
    GLD16(aP1 + k, As + (4 + wave) * 512);
    GLD16(bP + k, Bs + wave * 512);
    __syncthreads();
    bf16x8 af[4], bfr[2];
#pragma unroll
    for (int mi = 0; mi < 4; ++mi) af[mi] = *(const bf16x8*)(As + (wr * 4 + mi) * 512 + lane * 8);
#pragma unroll
    for (int ni = 0; ni < 2; ++ni) bfr[ni] = *(const bf16x8*)(Bs + (wc * 2 + ni) * 512 + lane * 8);
#pragma unroll
    for (int mi = 0; mi < 4; ++mi)
#pragma unroll
      for (int ni = 0; ni < 2; ++ni)
        acc[mi][ni] = __builtin_amdgcn_mfma_f32_16x16x32_bf16(af[mi], bfr[ni], acc[mi][ni], 0, 0, 0);
    __syncthreads();
  }

  const int cl = lane & 15, ql = lane >> 4;
#pragma unroll
  for (int mi = 0; mi < 4; ++mi) {
#pragma unroll
    for (int r = 0; r < 4; ++r) {
      const int slot = slotB + wr * 64 + mi * 16 + ql * 4 + r;
      const float c = row_scale[slot];  // 0 for padded slots -> zero fill
#pragma unroll
      for (int ni = 0; ni < 2; ++ni) {
        const int n = colBase + wc * 32 + ni * 16 + cl;  // interleaved col of w1
        float v = acc[mi][ni][r] + w1b[e * 2048 + n];
        float o = __shfl_xor(v, 1);  // partner column
        if ((lane & 1) == 0) {       // even lane = gate col
          float g = fminf(v, 7.f);
          float u = fminf(fmaxf(o, -7.f), 7.f);
          float sg = 1.f / (1.f + __expf(-1.702f * g));
          float a = (u + 1.f) * (g * sg);
          actS[(size_t)slot * 1024 + (n >> 1)] = f2bf(c * a);
        }
      }
    }
  }
}

// ---------------- GEMM2: 128x64 tile, split-K=2, atomic scatter into out ----------------
// 1-D grid 1280: d -> xcd(d&7), colSel(0..1), (work, ks); colIdx = xcd+8*colSel
__global__ __launch_bounds__(256) void gemm2_add_kernel(
    const u16* __restrict__ actS, const u16* __restrict__ w2t,
    const int* __restrict__ row_token, const int* __restrict__ meta,
    float* __restrict__ out) {
  const int d = blockIdx.x;
  const int xcd = d & 7, i = d >> 3;   // i: 0..159
  const int j = i >> 1;                // 0..79
  const int ks = (j >= 40) ? 1 : 0;
  const int work = j - ks * 40;
  if (work >= meta[0]) return;
  const int colBase = (xcd + ((i & 1) << 3)) << 6;   // 0..15 * 64
  const int k0 = ks << 9;
  const int wk = meta[1 + work];
  const int e = wk >> 8, rb = wk & 255;
  const int slotB = meta[48 + e] + (rb << 7);
  __shared__ __align__(16) u16 As[4096];
  __shared__ __align__(16) u16 Bs[2048];
  const int tid = threadIdx.x, lane = tid & 63, wave = tid >> 6;
  const int row16 = lane & 15, chunk = lane >> 4;
  const u16* Bt = w2t + (size_t)e * 1048576;
  const u16* aP0 = actS + (size_t)(slotB + wave * 16 + row16) * 1024 + chunk * 8;
  const u16* aP1 = actS + (size_t)(slotB + (wave + 4) * 16 + row16) * 1024 + chunk * 8;
  const u16* bP  = Bt + (size_t)(colBase + wave * 16 + row16) * 1024 + chunk * 8;
  const int wr = wave >> 1, wc = wave & 1;
  floatx4 acc[4][2];
#pragma unroll
  for (int mi = 0; mi < 4; ++mi)
#pragma unroll
    for (int ni = 0; ni < 2; ++ni) acc[mi][ni] = floatx4{0.f, 0.f, 0.f, 0.f};

  for (int kt = 0; kt < 16; ++kt) {
    const int k = k0 + kt * 32;
    GLD16(aP0 + k, As + wave * 512);
    GLD16(aP1 + k, As + (4 + wave) * 512);
    GLD16(bP + k, Bs + wave * 512);
    __syncthreads();
    bf16x8 af[4], bfr[2];
#pragma unroll
    for (int mi = 0; mi < 4; ++mi) af[mi] = *(const bf16x8*)(As + (wr * 4 + mi) * 512 + lane * 8);
#pragma unroll
    for (int ni = 0; ni < 2; ++ni) bfr[ni] = *(const bf16x8*)(Bs + (wc * 2 + ni) * 512 + lane * 8);
#pragma unroll
    for (int mi = 0; mi < 4; ++mi)
#pragma unroll
      for (int ni = 0; ni < 2; ++ni)
        acc[mi][ni] = __builtin_amdgcn_mfma_f32_16x16x32_bf16(af[mi], bfr[ni], acc[mi][ni], 0, 0, 0);
    __syncthreads();
  }

  const int cl = lane & 15, ql = lane >> 4;
#pragma unroll
  for (int mi = 0; mi < 4; ++mi)
#pragma unroll
    for (int r = 0; r < 4; ++r) {
      const int slot = slotB + wr * 64 + mi * 16 + ql * 4 + r;
      const int tok = row_token[slot];
      if (tok < 0) continue;
#pragma unroll
      for (int ni = 0; ni < 2; ++ni) {
        const int col = colBase + wc * 32 + ni * 16 + cl;
        atomicAdd(out + (size_t)tok * 1024 + col, acc[mi][ni][r]);
      }
    }
}

extern "C" void kernel_launch(void* const* d_in, const int* in_sizes, int n_in,
                              void* d_out, int out_size, void* d_ws, size_t ws_size,
                              hipStream_t stream) {
  const float* x   = (const float*)d_in[0];   // (2048, 1024)
  const float* rw  = (const float*)d_in[1];   // (8, 1024)
  const float* rb  = (const float*)d_in[2];   // (8,)
  const float* w1  = (const float*)d_in[3];   // (8, 1024, 2048)
  const float* w1b = (const float*)d_in[4];   // (8, 2048)
  const float* w2  = (const float*)d_in[5];   // (8, 1024, 1024)
  const float* w2b = (const float*)d_in[6];   // (8, 1024)
  float* out = (float*)d_out;                 // 2048*1024
  float* ew  = out + (size_t)2048 * 1024;     // 2048*2

  char* ws = (char*)d_ws;
  u16* xb        = (u16*)(ws);                                   //  4 MiB
  u16* w1t       = (u16*)(ws + (4ull << 20));                    // 32 MiB  (E, 2I, H)
  u16* w2t       = (u16*)(ws + (36ull << 20));                   // 16 MiB  (E, H, I)
  u16* actS      = (u16*)(ws + (52ull << 20));                   // 10 MiB  (5120, 1024)
  int* eids      = (int*)(ws + (62ull << 20));                   // 16 KiB
  float* eprobs  = (float*)(ws + (62ull << 20) + (16 << 10));    // 16 KiB
  int* row_token = (int*)(ws + (62ull << 20) + (32 << 10));      // 20 KiB
  float* row_scale = (float*)(ws + (62ull << 20) + (52 << 10));  // 20 KiB
  int* meta      = (int*)(ws + (62ull << 20) + (72 << 10));      // 1 KiB

  prep_kernel<<<13824, 256, 0, stream>>>(x, rw, rb, w1, w2, xb, w1t, w2t, ew, eids, eprobs);
  build_lists_kernel<<<1, 256, 0, stream>>>(eids, eprobs, row_token, row_scale, meta);
  bias_init_kernel<<<2048, 256, 0, stream>>>(eids, eprobs, w2b, out);
  gemm1_act_kernel<<<1280, 256, 0, stream>>>(xb, w1t, w1b, row_token, row_scale, meta, actS);
  gemm2_add_kernel<<<1280, 256, 0, stream>>>(actS, w2t, row_token, meta, out);
}